// Round 6
// baseline (182.324 us; speedup 1.0000x reference)
//
#include <hip/hip_runtime.h>
#include <hip/hip_bf16.h>
#include <cstdint>

#define NN   100000
#define NE   1600000
#define FIN  512
#define FHID 32
#define FOUT 16

#define BSHIFT 9
#define BSIZE  512
#define NBUCK  196                      // ceil(100000/512)
#define CPB    1024                     // edges per bin/hist pass
#define NCHUNK ((NE + CPB - 1) / CPB)   // 1563
#define NCSR   192                      // CSR-pipeline blocks
#define GEMMB  782                      // GEMM1 tile blocks
#define TOTB   (NCSR + GEMMB)

typedef float f32x4 __attribute__((ext_vector_type(4)));
typedef short s16x8 __attribute__((ext_vector_type(8)));
typedef short s16x4 __attribute__((ext_vector_type(4)));
typedef int   i32x4 __attribute__((ext_vector_type(4)));
typedef unsigned int u32;
typedef unsigned short u16;

__device__ __forceinline__ short f2bf(float f) {
  union { float f; uint32_t u; } v; v.f = f;
  uint32_t r = v.u + 0x7fffu + ((v.u >> 16) & 1u);
  return (short)(r >> 16);
}
__device__ __forceinline__ float bf2f(u16 u) {
  union { uint32_t u; float f; } v; v.u = (uint32_t)u << 16; return v.f;
}

// ---------------------------------------------------------------------------
// Fused kernel: blocks [0, NCSR) build the CSR (hist -> scan -> bin -> fin),
// blocks [NCSR, TOTB) compute H1[N,32](bf16, UNscaled) = x @ W1 via MFMA.
// CSR blocks sync among themselves with agent-scope atomic phase counters;
// GEMM blocks never wait on anything, so spin-waiters cannot deadlock.
// ---------------------------------------------------------------------------
struct BinSh {
  u32 cnt[NBUCK]; u32 lofs[NBUCK]; u32 gbase[NBUCK]; u32 tmp[256];
  u32 stage[CPB]; u16 sb[CPB];
};
struct FinSh { u32 degl[BSIZE]; u32 rsl[BSIZE]; u32 tmp[256]; };
union ShU {
  s16x8 B[16][2][64];     // 32 KB gemm W1 fragments
  u32 hist[NBUCK];
  u32 scan[256];
  BinSh bin;
  FinSh fin;
};

__global__ __launch_bounds__(256) void k_fused(
    const int* __restrict__ src, const int* __restrict__ dst,
    const float* __restrict__ x, const float* __restrict__ W1,
    u32* __restrict__ bcount, u32* __restrict__ ph,
    u32* __restrict__ bstart, u32* __restrict__ bcur,
    int* __restrict__ deg, int* __restrict__ rs, float* __restrict__ dinv,
    int* __restrict__ csr, u32* __restrict__ binned,
    u16* __restrict__ H1) {
  __shared__ ShU sh;
  const int tid = threadIdx.x;

  if (blockIdx.x < NCSR) {
    // ===================== CSR pipeline =====================
    const int cb = blockIdx.x;

    // ---- phase A: histogram of dst>>9 into global bcount ----
    for (int i = tid; i < NBUCK; i += 256) sh.hist[i] = 0;
    __syncthreads();
    for (int c = cb; c < NCHUNK; c += NCSR) {
      int e0 = c * CPB + tid * 4;
      if (e0 + 3 < NE) {
        i32x4 d4 = *(const i32x4*)(dst + e0);
        atomicAdd(&sh.hist[d4[0] >> BSHIFT], 1u);
        atomicAdd(&sh.hist[d4[1] >> BSHIFT], 1u);
        atomicAdd(&sh.hist[d4[2] >> BSHIFT], 1u);
        atomicAdd(&sh.hist[d4[3] >> BSHIFT], 1u);
      } else {
        for (int k = 0; k < 4; ++k)
          if (e0 + k < NE) atomicAdd(&sh.hist[dst[e0 + k] >> BSHIFT], 1u);
      }
    }
    __syncthreads();
    for (int i = tid; i < NBUCK; i += 256)
      if (sh.hist[i]) atomicAdd(&bcount[i], sh.hist[i]);
    __syncthreads();
    if (tid == 0)
      __hip_atomic_fetch_add(&ph[0], 1u, __ATOMIC_ACQ_REL, __HIP_MEMORY_SCOPE_AGENT);

    // ---- phase B: block 0 scans bucket counts -> bstart/bcur ----
    if (cb == 0) {
      if (tid == 0)
        while (__hip_atomic_load(&ph[0], __ATOMIC_ACQUIRE, __HIP_MEMORY_SCOPE_AGENT) < NCSR)
          __builtin_amdgcn_s_sleep(2);
      __syncthreads();
      u32 v = (tid < NBUCK) ? bcount[tid] : 0;
      sh.scan[tid] = v;
      __syncthreads();
      #pragma unroll
      for (int off = 1; off < 256; off <<= 1) {
        u32 t = (tid >= off) ? sh.scan[tid - off] : 0;
        __syncthreads();
        sh.scan[tid] += t;
        __syncthreads();
      }
      if (tid < NBUCK) {
        u32 e = sh.scan[tid] - v;
        bstart[tid] = e;
        bcur[tid] = e;
      }
      if (tid == 255) bstart[NBUCK] = sh.scan[255];
      __syncthreads();
      if (tid == 0)
        __hip_atomic_store(&ph[1], 1u, __ATOMIC_RELEASE, __HIP_MEMORY_SCOPE_AGENT);
    } else {
      if (tid == 0)
        while (__hip_atomic_load(&ph[1], __ATOMIC_ACQUIRE, __HIP_MEMORY_SCOPE_AGENT) < 1)
          __builtin_amdgcn_s_sleep(2);
      __syncthreads();
    }

    // ---- phase C: bin edges by bucket (coalesced binned writes) ----
    for (int c = cb; c < NCHUNK; c += NCSR) {
      for (int i = tid; i < NBUCK; i += 256) sh.bin.cnt[i] = 0;
      __syncthreads();
      int e0 = c * CPB + tid * 4;
      u32 vals[4]; u32 ofs[4]; int bks[4];
      if (e0 + 3 < NE) {
        i32x4 s4 = *(const i32x4*)(src + e0);
        i32x4 d4 = *(const i32x4*)(dst + e0);
        #pragma unroll
        for (int k = 0; k < 4; ++k) {
          int b = d4[k] >> BSHIFT;
          bks[k] = b;
          vals[k] = (u32)s4[k] | ((u32)(d4[k] & (BSIZE - 1)) << 17);
          ofs[k] = atomicAdd(&sh.bin.cnt[b], 1u);
        }
      } else {
        #pragma unroll
        for (int k = 0; k < 4; ++k) {
          int e = e0 + k;
          bool ok = e < NE;
          int s = 0, d = 0;
          if (ok) { s = src[e]; d = dst[e]; }
          int b = ok ? (d >> BSHIFT) : -1;
          bks[k] = b;
          vals[k] = (u32)s | ((u32)(d & (BSIZE - 1)) << 17);
          ofs[k] = ok ? atomicAdd(&sh.bin.cnt[b], 1u) : 0;
        }
      }
      __syncthreads();
      u32 cv = (tid < NBUCK) ? sh.bin.cnt[tid] : 0;
      sh.bin.tmp[tid] = cv;
      __syncthreads();
      #pragma unroll
      for (int off = 1; off < 256; off <<= 1) {
        u32 t = (tid >= off) ? sh.bin.tmp[tid - off] : 0;
        __syncthreads();
        sh.bin.tmp[tid] += t;
        __syncthreads();
      }
      if (tid < NBUCK) {
        sh.bin.lofs[tid] = sh.bin.tmp[tid] - cv;
        sh.bin.gbase[tid] = cv ? atomicAdd(&bcur[tid], cv) : 0;
      }
      __syncthreads();
      u32 total = sh.bin.tmp[255];
      __syncthreads();
      #pragma unroll
      for (int k = 0; k < 4; ++k) {
        if (bks[k] >= 0) {
          u32 sl = sh.bin.lofs[bks[k]] + ofs[k];
          sh.bin.stage[sl] = vals[k];
          sh.bin.sb[sl] = (u16)bks[k];
        }
      }
      __syncthreads();
      for (u32 s2 = tid; s2 < total; s2 += 256) {
        int b = sh.bin.sb[s2];
        binned[sh.bin.gbase[b] + (s2 - sh.bin.lofs[b])] = sh.bin.stage[s2];
      }
      __syncthreads();
    }
    if (tid == 0) {
      __hip_atomic_fetch_add(&ph[2], 1u, __ATOMIC_ACQ_REL, __HIP_MEMORY_SCOPE_AGENT);
      while (__hip_atomic_load(&ph[2], __ATOMIC_ACQUIRE, __HIP_MEMORY_SCOPE_AGENT) < NCSR)
        __builtin_amdgcn_s_sleep(2);
    }
    __syncthreads();

    // ---- phase D: finalize buckets -> deg/rs/dinv + csr ----
    for (int b = cb; b < NBUCK; b += NCSR) {
      u32 start = bstart[b];
      u32 n = bstart[b + 1] - start;
      sh.fin.degl[tid] = 0; sh.fin.degl[tid + 256] = 0;
      __syncthreads();
      for (u32 k = tid; k < n; k += 256)
        atomicAdd(&sh.fin.degl[binned[start + k] >> 17], 1u);
      __syncthreads();
      u32 a0 = sh.fin.degl[2 * tid], a1 = sh.fin.degl[2 * tid + 1];
      u32 s = a0 + a1;
      sh.fin.tmp[tid] = s;
      __syncthreads();
      #pragma unroll
      for (int off = 1; off < 256; off <<= 1) {
        u32 t = (tid >= off) ? sh.fin.tmp[tid - off] : 0;
        __syncthreads();
        sh.fin.tmp[tid] += t;
        __syncthreads();
      }
      u32 e = sh.fin.tmp[tid] - s;
      sh.fin.rsl[2 * tid] = e;
      sh.fin.rsl[2 * tid + 1] = e + a0;
      __syncthreads();
      #pragma unroll
      for (int q = 0; q < 2; ++q) {
        int t = tid + q * 256;
        int g = b * BSIZE + t;
        if (g < NN) {
          u32 dg = sh.fin.degl[t];
          deg[g] = (int)dg;
          rs[g] = (int)(start + sh.fin.rsl[t]);
          dinv[g] = rsqrtf(1.0f + (float)dg);
        }
      }
      __syncthreads();
      for (u32 k = tid; k < n; k += 256) {
        u32 vv = binned[start + k];
        u32 pos = atomicAdd(&sh.fin.rsl[vv >> 17], 1u);
        csr[start + pos] = (int)(vv & 0x1FFFFu);
      }
      __syncthreads();
    }
    return;
  }

  // ===================== GEMM1 tile =====================
  const int bid = blockIdx.x - NCSR;     // 0..781
  for (int it = 0; it < 64; ++it) {
    int flat = it * 256 + tid;
    int i  = flat & 7;
    int l  = (flat >> 3) & 63;
    int nt = (flat >> 9) & 1;
    int kt = flat >> 10;
    int k  = kt * 32 + ((l >> 4) << 3) + i;
    int n  = nt * 16 + (l & 15);
    ((short*)sh.B)[flat] = f2bf(W1[k * 32 + n]);
  }
  __syncthreads();

  const int lane = tid & 63;
  const int wv   = tid >> 6;
  const int h    = lane >> 4;
  const int m    = lane & 15;
  const int wid  = bid * 4 + wv;
  if (wid >= 3125) return;
  const int t0 = wid * 2;

  const float* xr0 = x + (size_t)(t0 * 16 + m) * FIN + h * 8;
  const float* xr1 = xr0 + (size_t)16 * FIN;

  f32x4 acc[2][2] = {};
  #pragma unroll
  for (int kt = 0; kt < 16; ++kt) {
    f32x4 a0 = *(const f32x4*)(xr0 + kt * 32);
    f32x4 a1 = *(const f32x4*)(xr0 + kt * 32 + 4);
    f32x4 c0 = *(const f32x4*)(xr1 + kt * 32);
    f32x4 c1 = *(const f32x4*)(xr1 + kt * 32 + 4);
    s16x8 b0 = sh.B[kt][0][lane];
    s16x8 b1 = sh.B[kt][1][lane];
    s16x8 af, cf;
    af[0]=f2bf(a0[0]); af[1]=f2bf(a0[1]); af[2]=f2bf(a0[2]); af[3]=f2bf(a0[3]);
    af[4]=f2bf(a1[0]); af[5]=f2bf(a1[1]); af[6]=f2bf(a1[2]); af[7]=f2bf(a1[3]);
    cf[0]=f2bf(c0[0]); cf[1]=f2bf(c0[1]); cf[2]=f2bf(c0[2]); cf[3]=f2bf(c0[3]);
    cf[4]=f2bf(c1[0]); cf[5]=f2bf(c1[1]); cf[6]=f2bf(c1[2]); cf[7]=f2bf(c1[3]);
    acc[0][0] = __builtin_amdgcn_mfma_f32_16x16x32_bf16(af, b0, acc[0][0], 0, 0, 0);
    acc[0][1] = __builtin_amdgcn_mfma_f32_16x16x32_bf16(af, b1, acc[0][1], 0, 0, 0);
    acc[1][0] = __builtin_amdgcn_mfma_f32_16x16x32_bf16(cf, b0, acc[1][0], 0, 0, 0);
    acc[1][1] = __builtin_amdgcn_mfma_f32_16x16x32_bf16(cf, b1, acc[1][1], 0, 0, 0);
  }
  #pragma unroll
  for (int rt = 0; rt < 2; ++rt) {
    #pragma unroll
    for (int r = 0; r < 4; ++r) {
      int row = (t0 + rt) * 16 + h * 4 + r;
      u16* o = H1 + (size_t)row * FHID + m;
      o[0]  = (u16)f2bf(acc[rt][0][r]);
      o[16] = (u16)f2bf(acc[rt][1][r]);
    }
  }
}

// ------ gather1 + relu + GEMM2 fused (4 lanes/node, 8 feats, ILP-8) ---------
// h1 = relu(dinv[d]*(Σ dinv[s]*H1[s] + dinv[d]*H1[d]) + b1); Hs2 = (h1@W2)*dinv[d]
__global__ __launch_bounds__(256) void k_gat1(const int* __restrict__ csr,
                                              const int* __restrict__ rs,
                                              const int* __restrict__ deg,
                                              const float* __restrict__ dinv,
                                              const float* __restrict__ b1,
                                              const float* __restrict__ W2,
                                              const u16* __restrict__ H1,
                                              u16* __restrict__ Hs2) {
  __shared__ float w[FHID * FOUT];
  for (int i = threadIdx.x; i < FHID * FOUT; i += 256) w[i] = W2[i];
  __syncthreads();

  int t = blockIdx.x * 256 + threadIdx.x;
  int d = t >> 2;
  if (d >= NN) return;
  int p = t & 3;
  int start = rs[d], n = deg[d];
  float dd = dinv[d];

  float a0[8], a1[8], a2[8], a3[8];
  {
    s16x8 v = *(const s16x8*)(H1 + (size_t)d * FHID + p * 8);  // self-loop
    #pragma unroll
    for (int k = 0; k < 8; ++k) {
      a0[k] = dd * bf2f((u16)v[k]); a1[k] = 0.f; a2[k] = 0.f; a3[k] = 0.f;
    }
  }
  int j = 0;
  for (; j + 8 <= n; j += 8) {
    int s0 = csr[start + j];
    int s1 = csr[start + j + 1];
    int s2 = csr[start + j + 2];
    int s3 = csr[start + j + 3];
    int s4 = csr[start + j + 4];
    int s5 = csr[start + j + 5];
    int s6 = csr[start + j + 6];
    int s7 = csr[start + j + 7];
    float d0 = dinv[s0], d1 = dinv[s1], d2 = dinv[s2], d3 = dinv[s3];
    float d4 = dinv[s4], d5 = dinv[s5], d6 = dinv[s6], d7 = dinv[s7];
    s16x8 v0 = *(const s16x8*)(H1 + (size_t)s0 * FHID + p * 8);
    s16x8 v1 = *(const s16x8*)(H1 + (size_t)s1 * FHID + p * 8);
    s16x8 v2 = *(const s16x8*)(H1 + (size_t)s2 * FHID + p * 8);
    s16x8 v3 = *(const s16x8*)(H1 + (size_t)s3 * FHID + p * 8);
    s16x8 v4 = *(const s16x8*)(H1 + (size_t)s4 * FHID + p * 8);
    s16x8 v5 = *(const s16x8*)(H1 + (size_t)s5 * FHID + p * 8);
    s16x8 v6 = *(const s16x8*)(H1 + (size_t)s6 * FHID + p * 8);
    s16x8 v7 = *(const s16x8*)(H1 + (size_t)s7 * FHID + p * 8);
    #pragma unroll
    for (int k = 0; k < 8; ++k) {
      a0[k] = fmaf(d0, bf2f((u16)v0[k]), a0[k]);
      a1[k] = fmaf(d1, bf2f((u16)v1[k]), a1[k]);
      a2[k] = fmaf(d2, bf2f((u16)v2[k]), a2[k]);
      a3[k] = fmaf(d3, bf2f((u16)v3[k]), a3[k]);
      a0[k] = fmaf(d4, bf2f((u16)v4[k]), a0[k]);
      a1[k] = fmaf(d5, bf2f((u16)v5[k]), a1[k]);
      a2[k] = fmaf(d6, bf2f((u16)v6[k]), a2[k]);
      a3[k] = fmaf(d7, bf2f((u16)v7[k]), a3[k]);
    }
  }
  for (; j + 4 <= n; j += 4) {
    int s0 = csr[start + j];
    int s1 = csr[start + j + 1];
    int s2 = csr[start + j + 2];
    int s3 = csr[start + j + 3];
    float d0 = dinv[s0], d1 = dinv[s1], d2 = dinv[s2], d3 = dinv[s3];
    s16x8 v0 = *(const s16x8*)(H1 + (size_t)s0 * FHID + p * 8);
    s16x8 v1 = *(const s16x8*)(H1 + (size_t)s1 * FHID + p * 8);
    s16x8 v2 = *(const s16x8*)(H1 + (size_t)s2 * FHID + p * 8);
    s16x8 v3 = *(const s16x8*)(H1 + (size_t)s3 * FHID + p * 8);
    #pragma unroll
    for (int k = 0; k < 8; ++k) {
      a0[k] = fmaf(d0, bf2f((u16)v0[k]), a0[k]);
      a1[k] = fmaf(d1, bf2f((u16)v1[k]), a1[k]);
      a2[k] = fmaf(d2, bf2f((u16)v2[k]), a2[k]);
      a3[k] = fmaf(d3, bf2f((u16)v3[k]), a3[k]);
    }
  }
  for (; j < n; ++j) {
    int s0 = csr[start + j];
    float d0 = dinv[s0];
    s16x8 v0 = *(const s16x8*)(H1 + (size_t)s0 * FHID + p * 8);
    #pragma unroll
    for (int k = 0; k < 8; ++k) a0[k] = fmaf(d0, bf2f((u16)v0[k]), a0[k]);
  }

  float h[8];
  #pragma unroll
  for (int k = 0; k < 8; ++k)
    h[k] = fmaxf(((a0[k] + a1[k]) + (a2[k] + a3[k])) * dd + b1[p * 8 + k], 0.0f);

  float pj[FOUT];
  #pragma unroll
  for (int jj = 0; jj < FOUT; ++jj) pj[jj] = 0.f;
  #pragma unroll
  for (int k = 0; k < 8; ++k)
    #pragma unroll
    for (int jj = 0; jj < FOUT; ++jj)
      pj[jj] = fmaf(h[k], w[(p * 8 + k) * FOUT + jj], pj[jj]);
  #pragma unroll
  for (int jj = 0; jj < FOUT; ++jj) {
    pj[jj] += __shfl_xor(pj[jj], 1);
    pj[jj] += __shfl_xor(pj[jj], 2);
  }
  s16x4 o;
  #pragma unroll
  for (int q = 0; q < 4; ++q) o[q] = f2bf(pj[p * 4 + q] * dd);
  *(s16x4*)(Hs2 + (size_t)d * FOUT + p * 4) = o;
}

// ------ gather2 + bias + log_softmax (4 lanes/node, 4 feats, ILP-8) ---------
__global__ __launch_bounds__(256) void k_gat2(const int* __restrict__ csr,
                                              const int* __restrict__ rs,
                                              const int* __restrict__ deg,
                                              const float* __restrict__ dinv,
                                              const float* __restrict__ b2,
                                              const u16* __restrict__ Hs2,
                                              float* __restrict__ out) {
  int t = blockIdx.x * 256 + threadIdx.x;
  int d = t >> 2;
  if (d >= NN) return;
  int p = t & 3;
  int start = rs[d], n = deg[d];

  float a0[4], a1[4], a2[4], a3[4];
  {
    s16x4 v = *(const s16x4*)(Hs2 + (size_t)d * FOUT + p * 4);  // self-loop
    #pragma unroll
    for (int k = 0; k < 4; ++k) {
      a0[k] = bf2f((u16)v[k]); a1[k] = 0.f; a2[k] = 0.f; a3[k] = 0.f;
    }
  }
  int j = 0;
  for (; j + 8 <= n; j += 8) {
    int s0 = csr[start + j];
    int s1 = csr[start + j + 1];
    int s2 = csr[start + j + 2];
    int s3 = csr[start + j + 3];
    int s4 = csr[start + j + 4];
    int s5 = csr[start + j + 5];
    int s6 = csr[start + j + 6];
    int s7 = csr[start + j + 7];
    s16x4 v0 = *(const s16x4*)(Hs2 + (size_t)s0 * FOUT + p * 4);
    s16x4 v1 = *(const s16x4*)(Hs2 + (size_t)s1 * FOUT + p * 4);
    s16x4 v2 = *(const s16x4*)(Hs2 + (size_t)s2 * FOUT + p * 4);
    s16x4 v3 = *(const s16x4*)(Hs2 + (size_t)s3 * FOUT + p * 4);
    s16x4 v4 = *(const s16x4*)(Hs2 + (size_t)s4 * FOUT + p * 4);
    s16x4 v5 = *(const s16x4*)(Hs2 + (size_t)s5 * FOUT + p * 4);
    s16x4 v6 = *(const s16x4*)(Hs2 + (size_t)s6 * FOUT + p * 4);
    s16x4 v7 = *(const s16x4*)(Hs2 + (size_t)s7 * FOUT + p * 4);
    #pragma unroll
    for (int k = 0; k < 4; ++k) {
      a0[k] += bf2f((u16)v0[k]);
      a1[k] += bf2f((u16)v1[k]);
      a2[k] += bf2f((u16)v2[k]);
      a3[k] += bf2f((u16)v3[k]);
      a0[k] += bf2f((u16)v4[k]);
      a1[k] += bf2f((u16)v5[k]);
      a2[k] += bf2f((u16)v6[k]);
      a3[k] += bf2f((u16)v7[k]);
    }
  }
  for (; j + 4 <= n; j += 4) {
    int s0 = csr[start + j];
    int s1 = csr[start + j + 1];
    int s2 = csr[start + j + 2];
    int s3 = csr[start + j + 3];
    s16x4 v0 = *(const s16x4*)(Hs2 + (size_t)s0 * FOUT + p * 4);
    s16x4 v1 = *(const s16x4*)(Hs2 + (size_t)s1 * FOUT + p * 4);
    s16x4 v2 = *(const s16x4*)(Hs2 + (size_t)s2 * FOUT + p * 4);
    s16x4 v3 = *(const s16x4*)(Hs2 + (size_t)s3 * FOUT + p * 4);
    #pragma unroll
    for (int k = 0; k < 4; ++k) {
      a0[k] += bf2f((u16)v0[k]);
      a1[k] += bf2f((u16)v1[k]);
      a2[k] += bf2f((u16)v2[k]);
      a3[k] += bf2f((u16)v3[k]);
    }
  }
  for (; j < n; ++j) {
    int s0 = csr[start + j];
    s16x4 v0 = *(const s16x4*)(Hs2 + (size_t)s0 * FOUT + p * 4);
    #pragma unroll
    for (int k = 0; k < 4; ++k) a0[k] += bf2f((u16)v0[k]);
  }

  float dd = dinv[d];
  float z[4];
  #pragma unroll
  for (int k = 0; k < 4; ++k)
    z[k] = ((a0[k] + a1[k]) + (a2[k] + a3[k])) * dd + b2[p * 4 + k];

  float m = fmaxf(fmaxf(z[0], z[1]), fmaxf(z[2], z[3]));
  m = fmaxf(m, __shfl_xor(m, 1));
  m = fmaxf(m, __shfl_xor(m, 2));
  float s = expf(z[0]-m) + expf(z[1]-m) + expf(z[2]-m) + expf(z[3]-m);
  s += __shfl_xor(s, 1);
  s += __shfl_xor(s, 2);
  float lse = m + logf(s);

  f32x4 o = { z[0]-lse, z[1]-lse, z[2]-lse, z[3]-lse };
  *(f32x4*)(out + (size_t)d * FOUT + p * 4) = o;
}

extern "C" void kernel_launch(void* const* d_in, const int* in_sizes, int n_in,
                              void* d_out, int out_size, void* d_ws, size_t ws_size,
                              hipStream_t stream) {
  const float* x  = (const float*)d_in[0];
  const float* W1 = (const float*)d_in[1];
  const float* b1 = (const float*)d_in[2];
  const float* W2 = (const float*)d_in[3];
  const float* b2 = (const float*)d_in[4];
  const int*   ei = (const int*)d_in[5];
  const int* srcv = ei;
  const int* dstv = ei + NE;

  char* ws = (char*)d_ws;
  const size_t KB = 1024, MB = 1048576;
  u32*   bcount = (u32*)(ws + 0);           // 784 B
  u32*   ph     = (u32*)(ws + 1 * KB);      // 32 B phase counters
  u32*   bstart = (u32*)(ws + 8 * KB);      // 788 B
  u32*   bcur   = (u32*)(ws + 16 * KB);     // 784 B
  int*   deg    = (int*)(ws + 512 * KB);    // 0.4 MB
  int*   rs     = (int*)(ws + 1024 * KB);   // 0.4 MB
  float* dinv   = (float*)(ws + 1536 * KB); // 0.4 MB
  u32*   binned = (u32*)(ws + 2 * MB);      // 6.4 MB
  int*   csr    = (int*)(ws + 9 * MB);      // 6.4 MB
  u16*   H1     = (u16*)(ws + 16 * MB);     // 6.4 MB (bf16, unscaled)
  u16*   Hs2    = (u16*)(ws + 23 * MB);     // 3.2 MB (bf16)
  float* out    = (float*)d_out;

  // zero bcount + phase counters (one small memset)
  hipMemsetAsync(ws, 0, 2 * KB, stream);

  k_fused<<<TOTB, 256, 0, stream>>>(srcv, dstv, x, W1, bcount, ph,
                                    bstart, bcur, deg, rs, dinv, csr, binned, H1);
  k_gat1 <<<(NN * 4 + 255) / 256, 256, 0, stream>>>(csr, rs, deg, dinv, b1, W2, H1, Hs2);
  k_gat2 <<<(NN * 4 + 255) / 256, 256, 0, stream>>>(csr, rs, deg, dinv, b2, Hs2, out);
}

// Round 7
// 177.364 us; speedup vs baseline: 1.0280x; 1.0280x over previous
//
#include <hip/hip_runtime.h>
#include <hip/hip_bf16.h>
#include <cstdint>

#define NN   100000
#define NE   1600000
#define FIN  512
#define FHID 32
#define FOUT 16

#define BSHIFT 9
#define BSIZE  512
#define NBUCK  196                      // ceil(100000/512)
#define HEPB   4096                     // edges per hist block
#define NHB    ((NE + HEPB - 1) / HEPB) // 391
#define BEPB   2048                     // edges per bin block
#define NBB    ((NE + BEPB - 1) / BEPB) // 782

typedef float f32x4 __attribute__((ext_vector_type(4)));
typedef short s16x8 __attribute__((ext_vector_type(8)));
typedef short s16x4 __attribute__((ext_vector_type(4)));
typedef int   i32x4 __attribute__((ext_vector_type(4)));
typedef unsigned int u32;
typedef unsigned short u16;

__device__ __forceinline__ short f2bf(float f) {
  union { float f; uint32_t u; } v; v.f = f;
  uint32_t r = v.u + 0x7fffu + ((v.u >> 16) & 1u);
  return (short)(r >> 16);
}
__device__ __forceinline__ float bf2f(u16 u) {
  union { uint32_t u; float f; } v; v.u = (uint32_t)u << 16; return v.f;
}

// ------ hist of dst>>9 + last-block scan -> bstart/bcur ---------------------
__global__ __launch_bounds__(256) void k_hist(const int* __restrict__ dst,
                                              u32* __restrict__ bcount,
                                              u32* __restrict__ ticket,
                                              u32* __restrict__ bstart,
                                              u32* __restrict__ bcur) {
  __shared__ u32 h[256];
  __shared__ bool amlast;
  int tid = threadIdx.x;
  h[tid] = 0;
  __syncthreads();
  int base = blockIdx.x * HEPB;
  #pragma unroll
  for (int i = 0; i < HEPB / 1024; ++i) {
    int e0 = base + (i * 256 + tid) * 4;
    if (e0 + 3 < NE) {
      i32x4 d4 = *(const i32x4*)(dst + e0);
      atomicAdd(&h[d4[0] >> BSHIFT], 1u);
      atomicAdd(&h[d4[1] >> BSHIFT], 1u);
      atomicAdd(&h[d4[2] >> BSHIFT], 1u);
      atomicAdd(&h[d4[3] >> BSHIFT], 1u);
    } else {
      for (int k = 0; k < 4; ++k)
        if (e0 + k < NE) atomicAdd(&h[dst[e0 + k] >> BSHIFT], 1u);
    }
  }
  __syncthreads();
  if (tid < NBUCK && h[tid]) atomicAdd(&bcount[tid], h[tid]);
  __syncthreads();
  if (tid == 0) {
    __threadfence();
    u32 t = __hip_atomic_fetch_add(ticket, 1u, __ATOMIC_ACQ_REL, __HIP_MEMORY_SCOPE_AGENT);
    amlast = (t == gridDim.x - 1);
  }
  __syncthreads();
  if (!amlast) return;
  // last block: exclusive scan of bcount -> bstart, bcur
  u32 v = (tid < NBUCK)
        ? __hip_atomic_load(&bcount[tid], __ATOMIC_RELAXED, __HIP_MEMORY_SCOPE_AGENT) : 0;
  h[tid] = v;
  __syncthreads();
  #pragma unroll
  for (int off = 1; off < 256; off <<= 1) {
    u32 t = (tid >= off) ? h[tid - off] : 0;
    __syncthreads();
    h[tid] += t;
    __syncthreads();
  }
  if (tid < NBUCK) { u32 e = h[tid] - v; bstart[tid] = e; bcur[tid] = e; }
  if (tid == 255) bstart[NBUCK] = h[255];
}

// ---------------- bin edges by bucket, coalesced writes ---------------------
__global__ __launch_bounds__(512) void k_bin(const int* __restrict__ src,
                                             const int* __restrict__ dst,
                                             u32* __restrict__ bcur,
                                             u32* __restrict__ binned) {
  __shared__ u32 cnt[NBUCK];
  __shared__ u32 lofs[NBUCK];
  __shared__ u32 gbase[NBUCK];
  __shared__ u32 tmp[512];
  __shared__ u32 stage[BEPB];
  __shared__ u16 sb[BEPB];
  int tid = threadIdx.x;
  for (int i = tid; i < NBUCK; i += 512) cnt[i] = 0;
  __syncthreads();

  int base = blockIdx.x * BEPB;
  int e0 = base + tid * 4;
  u32 vals[4]; u32 ofs[4]; int bks[4];
  if (e0 + 3 < NE) {
    i32x4 s4 = *(const i32x4*)(src + e0);
    i32x4 d4 = *(const i32x4*)(dst + e0);
    #pragma unroll
    for (int k = 0; k < 4; ++k) {
      int b = d4[k] >> BSHIFT;
      bks[k] = b;
      vals[k] = (u32)s4[k] | ((u32)(d4[k] & (BSIZE - 1)) << 17);
      ofs[k] = atomicAdd(&cnt[b], 1u);
    }
  } else {
    #pragma unroll
    for (int k = 0; k < 4; ++k) {
      int e = e0 + k;
      bool ok = e < NE;
      int s = 0, d = 0;
      if (ok) { s = src[e]; d = dst[e]; }
      int b = ok ? (d >> BSHIFT) : -1;
      bks[k] = b;
      vals[k] = (u32)s | ((u32)(d & (BSIZE - 1)) << 17);
      ofs[k] = ok ? atomicAdd(&cnt[b], 1u) : 0;
    }
  }
  __syncthreads();

  u32 cv = (tid < NBUCK) ? cnt[tid] : 0;
  tmp[tid] = cv;
  __syncthreads();
  #pragma unroll
  for (int off = 1; off < 512; off <<= 1) {
    u32 t = (tid >= off) ? tmp[tid - off] : 0;
    __syncthreads();
    tmp[tid] += t;
    __syncthreads();
  }
  if (tid < NBUCK) {
    lofs[tid] = tmp[tid] - cv;
    gbase[tid] = cv ? atomicAdd(&bcur[tid], cv) : 0;
  }
  __syncthreads();
  u32 total = tmp[511];
  __syncthreads();

  #pragma unroll
  for (int k = 0; k < 4; ++k) {
    if (bks[k] >= 0) {
      u32 sl = lofs[bks[k]] + ofs[k];
      stage[sl] = vals[k];
      sb[sl] = (u16)bks[k];
    }
  }
  __syncthreads();

  for (u32 s2 = tid; s2 < total; s2 += 512) {
    int b = sb[s2];
    binned[gbase[b] + (s2 - lofs[b])] = stage[s2];
  }
}

// ------- finalize per bucket: deg/dinv/rs + csr (block-local writes) --------
__global__ __launch_bounds__(256) void k_fin(const u32* __restrict__ binned,
                                             const u32* __restrict__ bstart,
                                             int* __restrict__ deg,
                                             int* __restrict__ rs,
                                             float* __restrict__ dinv,
                                             int* __restrict__ csr) {
  __shared__ u32 degl[BSIZE];
  __shared__ u32 rsl[BSIZE];
  __shared__ u32 tmp[256];
  int tid = threadIdx.x;
  int b = blockIdx.x;
  u32 start = bstart[b];
  u32 n = bstart[b + 1] - start;

  degl[tid] = 0; degl[tid + 256] = 0;
  __syncthreads();
  for (u32 k = tid; k < n; k += 256)
    atomicAdd(&degl[binned[start + k] >> 17], 1u);
  __syncthreads();

  u32 a0 = degl[2 * tid], a1 = degl[2 * tid + 1];
  u32 s = a0 + a1;
  tmp[tid] = s;
  __syncthreads();
  #pragma unroll
  for (int off = 1; off < 256; off <<= 1) {
    u32 t = (tid >= off) ? tmp[tid - off] : 0;
    __syncthreads();
    tmp[tid] += t;
    __syncthreads();
  }
  u32 e = tmp[tid] - s;
  rsl[2 * tid] = e;
  rsl[2 * tid + 1] = e + a0;
  __syncthreads();

  #pragma unroll
  for (int q = 0; q < 2; ++q) {
    int t = tid + q * 256;
    int g = b * BSIZE + t;
    if (g < NN) {
      u32 dg = degl[t];
      deg[g] = (int)dg;
      rs[g] = (int)(start + rsl[t]);
      dinv[g] = rsqrtf(1.0f + (float)dg);
    }
  }
  __syncthreads();

  for (u32 k = tid; k < n; k += 256) {
    u32 vv = binned[start + k];
    u32 pos = atomicAdd(&rsl[vv >> 17], 1u);
    csr[start + pos] = (int)(vv & 0x1FFFFu);
  }
}

// ------- GEMM1: Hs1a/b[N,16](bf16) = halves of (x @ W1) * dinv[row] --------
__global__ __launch_bounds__(256) void k_gemm1(const float* __restrict__ x,
                                               const float* __restrict__ W1,
                                               const float* __restrict__ dinv,
                                               u16* __restrict__ Hs1a,
                                               u16* __restrict__ Hs1b) {
  __shared__ s16x8 Blds[16][2][64];
  const int tid = threadIdx.x;
  for (int it = 0; it < 64; ++it) {
    int flat = it * 256 + tid;
    int i  = flat & 7;
    int l  = (flat >> 3) & 63;
    int nt = (flat >> 9) & 1;
    int kt = flat >> 10;
    int k  = kt * 32 + ((l >> 4) << 3) + i;
    int n  = nt * 16 + (l & 15);
    ((short*)Blds)[flat] = f2bf(W1[k * 32 + n]);
  }
  __syncthreads();

  const int lane = tid & 63;
  const int wv   = tid >> 6;
  const int h    = lane >> 4;
  const int m    = lane & 15;
  const int wid  = blockIdx.x * 4 + wv;
  if (wid >= 3125) return;
  const int t0 = wid * 2;

  const float* xr0 = x + (size_t)(t0 * 16 + m) * FIN + h * 8;
  const float* xr1 = xr0 + (size_t)16 * FIN;

  f32x4 acc[2][2] = {};
  #pragma unroll
  for (int kt = 0; kt < 16; ++kt) {
    f32x4 a0 = *(const f32x4*)(xr0 + kt * 32);
    f32x4 a1 = *(const f32x4*)(xr0 + kt * 32 + 4);
    f32x4 c0 = *(const f32x4*)(xr1 + kt * 32);
    f32x4 c1 = *(const f32x4*)(xr1 + kt * 32 + 4);
    s16x8 b0 = Blds[kt][0][lane];
    s16x8 b1 = Blds[kt][1][lane];
    s16x8 af, cf;
    af[0]=f2bf(a0[0]); af[1]=f2bf(a0[1]); af[2]=f2bf(a0[2]); af[3]=f2bf(a0[3]);
    af[4]=f2bf(a1[0]); af[5]=f2bf(a1[1]); af[6]=f2bf(a1[2]); af[7]=f2bf(a1[3]);
    cf[0]=f2bf(c0[0]); cf[1]=f2bf(c0[1]); cf[2]=f2bf(c0[2]); cf[3]=f2bf(c0[3]);
    cf[4]=f2bf(c1[0]); cf[5]=f2bf(c1[1]); cf[6]=f2bf(c1[2]); cf[7]=f2bf(c1[3]);
    acc[0][0] = __builtin_amdgcn_mfma_f32_16x16x32_bf16(af, b0, acc[0][0], 0, 0, 0);
    acc[0][1] = __builtin_amdgcn_mfma_f32_16x16x32_bf16(af, b1, acc[0][1], 0, 0, 0);
    acc[1][0] = __builtin_amdgcn_mfma_f32_16x16x32_bf16(cf, b0, acc[1][0], 0, 0, 0);
    acc[1][1] = __builtin_amdgcn_mfma_f32_16x16x32_bf16(cf, b1, acc[1][1], 0, 0, 0);
  }
  #pragma unroll
  for (int rt = 0; rt < 2; ++rt) {
    #pragma unroll
    for (int r = 0; r < 4; ++r) {
      int row = (t0 + rt) * 16 + h * 4 + r;
      float di = dinv[row];
      Hs1a[(size_t)row * 16 + m] = (u16)f2bf(acc[rt][0][r] * di);
      Hs1b[(size_t)row * 16 + m] = (u16)f2bf(acc[rt][1][r] * di);
    }
  }
}

// ------ gather1 half-pass A: partial GEMM2 products into P2 (f32) ----------
// 4 lanes/node, 4 feats each, features 0..15 (Hs1a, 3.2MB = L2-resident)
__global__ __launch_bounds__(256) void k_gat1a(const int* __restrict__ csr,
                                               const int* __restrict__ rs,
                                               const int* __restrict__ deg,
                                               const float* __restrict__ dinv,
                                               const float* __restrict__ b1,
                                               const float* __restrict__ W2,
                                               const u16* __restrict__ Hs1a,
                                               float* __restrict__ P2) {
  __shared__ float w[256];
  w[threadIdx.x] = W2[threadIdx.x];          // rows 0..15
  __syncthreads();
  int t = blockIdx.x * 256 + threadIdx.x;
  int d = t >> 2;
  if (d >= NN) return;
  int p = t & 3;
  int start = rs[d], n = deg[d];

  float a0[4], a1[4], a2[4], a3[4];
  {
    s16x4 v = *(const s16x4*)(Hs1a + (size_t)d * 16 + p * 4);
    #pragma unroll
    for (int k = 0; k < 4; ++k) { a0[k] = bf2f((u16)v[k]); a1[k]=0.f; a2[k]=0.f; a3[k]=0.f; }
  }
  int j = 0;
  for (; j + 8 <= n; j += 8) {
    int s0=csr[start+j],   s1=csr[start+j+1], s2=csr[start+j+2], s3=csr[start+j+3];
    int s4=csr[start+j+4], s5=csr[start+j+5], s6=csr[start+j+6], s7=csr[start+j+7];
    s16x4 v0 = *(const s16x4*)(Hs1a + (size_t)s0 * 16 + p * 4);
    s16x4 v1 = *(const s16x4*)(Hs1a + (size_t)s1 * 16 + p * 4);
    s16x4 v2 = *(const s16x4*)(Hs1a + (size_t)s2 * 16 + p * 4);
    s16x4 v3 = *(const s16x4*)(Hs1a + (size_t)s3 * 16 + p * 4);
    s16x4 v4 = *(const s16x4*)(Hs1a + (size_t)s4 * 16 + p * 4);
    s16x4 v5 = *(const s16x4*)(Hs1a + (size_t)s5 * 16 + p * 4);
    s16x4 v6 = *(const s16x4*)(Hs1a + (size_t)s6 * 16 + p * 4);
    s16x4 v7 = *(const s16x4*)(Hs1a + (size_t)s7 * 16 + p * 4);
    #pragma unroll
    for (int k = 0; k < 4; ++k) {
      a0[k] += bf2f((u16)v0[k]); a1[k] += bf2f((u16)v1[k]);
      a2[k] += bf2f((u16)v2[k]); a3[k] += bf2f((u16)v3[k]);
      a0[k] += bf2f((u16)v4[k]); a1[k] += bf2f((u16)v5[k]);
      a2[k] += bf2f((u16)v6[k]); a3[k] += bf2f((u16)v7[k]);
    }
  }
  for (; j < n; ++j) {
    int s0 = csr[start + j];
    s16x4 v0 = *(const s16x4*)(Hs1a + (size_t)s0 * 16 + p * 4);
    #pragma unroll
    for (int k = 0; k < 4; ++k) a0[k] += bf2f((u16)v0[k]);
  }

  float dd = dinv[d];
  float h[4];
  #pragma unroll
  for (int k = 0; k < 4; ++k)
    h[k] = fmaxf(((a0[k]+a1[k]) + (a2[k]+a3[k])) * dd + b1[p * 4 + k], 0.0f);

  float pj[FOUT];
  #pragma unroll
  for (int jj = 0; jj < FOUT; ++jj) pj[jj] = 0.f;
  #pragma unroll
  for (int k = 0; k < 4; ++k)
    #pragma unroll
    for (int jj = 0; jj < FOUT; ++jj)
      pj[jj] = fmaf(h[k], w[(p * 4 + k) * FOUT + jj], pj[jj]);
  #pragma unroll
  for (int jj = 0; jj < FOUT; ++jj) {
    pj[jj] += __shfl_xor(pj[jj], 1);
    pj[jj] += __shfl_xor(pj[jj], 2);
  }
  f32x4 o = { pj[p*4+0], pj[p*4+1], pj[p*4+2], pj[p*4+3] };
  *(f32x4*)(P2 + (size_t)d * FOUT + p * 4) = o;
}

// ------ gather1 half-pass B: add partials, scale, write Hs2 (bf16) ---------
__global__ __launch_bounds__(256) void k_gat1b(const int* __restrict__ csr,
                                               const int* __restrict__ rs,
                                               const int* __restrict__ deg,
                                               const float* __restrict__ dinv,
                                               const float* __restrict__ b1,
                                               const float* __restrict__ W2,
                                               const u16* __restrict__ Hs1b,
                                               const float* __restrict__ P2,
                                               u16* __restrict__ Hs2) {
  __shared__ float w[256];
  w[threadIdx.x] = W2[256 + threadIdx.x];    // rows 16..31
  __syncthreads();
  int t = blockIdx.x * 256 + threadIdx.x;
  int d = t >> 2;
  if (d >= NN) return;
  int p = t & 3;
  int start = rs[d], n = deg[d];

  float a0[4], a1[4], a2[4], a3[4];
  {
    s16x4 v = *(const s16x4*)(Hs1b + (size_t)d * 16 + p * 4);
    #pragma unroll
    for (int k = 0; k < 4; ++k) { a0[k] = bf2f((u16)v[k]); a1[k]=0.f; a2[k]=0.f; a3[k]=0.f; }
  }
  int j = 0;
  for (; j + 8 <= n; j += 8) {
    int s0=csr[start+j],   s1=csr[start+j+1], s2=csr[start+j+2], s3=csr[start+j+3];
    int s4=csr[start+j+4], s5=csr[start+j+5], s6=csr[start+j+6], s7=csr[start+j+7];
    s16x4 v0 = *(const s16x4*)(Hs1b + (size_t)s0 * 16 + p * 4);
    s16x4 v1 = *(const s16x4*)(Hs1b + (size_t)s1 * 16 + p * 4);
    s16x4 v2 = *(const s16x4*)(Hs1b + (size_t)s2 * 16 + p * 4);
    s16x4 v3 = *(const s16x4*)(Hs1b + (size_t)s3 * 16 + p * 4);
    s16x4 v4 = *(const s16x4*)(Hs1b + (size_t)s4 * 16 + p * 4);
    s16x4 v5 = *(const s16x4*)(Hs1b + (size_t)s5 * 16 + p * 4);
    s16x4 v6 = *(const s16x4*)(Hs1b + (size_t)s6 * 16 + p * 4);
    s16x4 v7 = *(const s16x4*)(Hs1b + (size_t)s7 * 16 + p * 4);
    #pragma unroll
    for (int k = 0; k < 4; ++k) {
      a0[k] += bf2f((u16)v0[k]); a1[k] += bf2f((u16)v1[k]);
      a2[k] += bf2f((u16)v2[k]); a3[k] += bf2f((u16)v3[k]);
      a0[k] += bf2f((u16)v4[k]); a1[k] += bf2f((u16)v5[k]);
      a2[k] += bf2f((u16)v6[k]); a3[k] += bf2f((u16)v7[k]);
    }
  }
  for (; j < n; ++j) {
    int s0 = csr[start + j];
    s16x4 v0 = *(const s16x4*)(Hs1b + (size_t)s0 * 16 + p * 4);
    #pragma unroll
    for (int k = 0; k < 4; ++k) a0[k] += bf2f((u16)v0[k]);
  }

  float dd = dinv[d];
  float h[4];
  #pragma unroll
  for (int k = 0; k < 4; ++k)
    h[k] = fmaxf(((a0[k]+a1[k]) + (a2[k]+a3[k])) * dd + b1[16 + p * 4 + k], 0.0f);

  float pj[FOUT];
  #pragma unroll
  for (int jj = 0; jj < FOUT; ++jj) pj[jj] = 0.f;
  #pragma unroll
  for (int k = 0; k < 4; ++k)
    #pragma unroll
    for (int jj = 0; jj < FOUT; ++jj)
      pj[jj] = fmaf(h[k], w[(p * 4 + k) * FOUT + jj], pj[jj]);
  #pragma unroll
  for (int jj = 0; jj < FOUT; ++jj) {
    pj[jj] += __shfl_xor(pj[jj], 1);
    pj[jj] += __shfl_xor(pj[jj], 2);
  }
  f32x4 prev = *(const f32x4*)(P2 + (size_t)d * FOUT + p * 4);
  s16x4 o;
  #pragma unroll
  for (int q = 0; q < 4; ++q) o[q] = f2bf((pj[p*4+q] + prev[q]) * dd);
  *(s16x4*)(Hs2 + (size_t)d * FOUT + p * 4) = o;
}

// ------ gather2 + bias + log_softmax (4 lanes/node, 4 feats, ILP-8) ---------
__global__ __launch_bounds__(256) void k_gat2(const int* __restrict__ csr,
                                              const int* __restrict__ rs,
                                              const int* __restrict__ deg,
                                              const float* __restrict__ dinv,
                                              const float* __restrict__ b2,
                                              const u16* __restrict__ Hs2,
                                              float* __restrict__ out) {
  int t = blockIdx.x * 256 + threadIdx.x;
  int d = t >> 2;
  if (d >= NN) return;
  int p = t & 3;
  int start = rs[d], n = deg[d];

  float a0[4], a1[4], a2[4], a3[4];
  {
    s16x4 v = *(const s16x4*)(Hs2 + (size_t)d * FOUT + p * 4);
    #pragma unroll
    for (int k = 0; k < 4; ++k) { a0[k] = bf2f((u16)v[k]); a1[k]=0.f; a2[k]=0.f; a3[k]=0.f; }
  }
  int j = 0;
  for (; j + 8 <= n; j += 8) {
    int s0=csr[start+j],   s1=csr[start+j+1], s2=csr[start+j+2], s3=csr[start+j+3];
    int s4=csr[start+j+4], s5=csr[start+j+5], s6=csr[start+j+6], s7=csr[start+j+7];
    s16x4 v0 = *(const s16x4*)(Hs2 + (size_t)s0 * FOUT + p * 4);
    s16x4 v1 = *(const s16x4*)(Hs2 + (size_t)s1 * FOUT + p * 4);
    s16x4 v2 = *(const s16x4*)(Hs2 + (size_t)s2 * FOUT + p * 4);
    s16x4 v3 = *(const s16x4*)(Hs2 + (size_t)s3 * FOUT + p * 4);
    s16x4 v4 = *(const s16x4*)(Hs2 + (size_t)s4 * FOUT + p * 4);
    s16x4 v5 = *(const s16x4*)(Hs2 + (size_t)s5 * FOUT + p * 4);
    s16x4 v6 = *(const s16x4*)(Hs2 + (size_t)s6 * FOUT + p * 4);
    s16x4 v7 = *(const s16x4*)(Hs2 + (size_t)s7 * FOUT + p * 4);
    #pragma unroll
    for (int k = 0; k < 4; ++k) {
      a0[k] += bf2f((u16)v0[k]); a1[k] += bf2f((u16)v1[k]);
      a2[k] += bf2f((u16)v2[k]); a3[k] += bf2f((u16)v3[k]);
      a0[k] += bf2f((u16)v4[k]); a1[k] += bf2f((u16)v5[k]);
      a2[k] += bf2f((u16)v6[k]); a3[k] += bf2f((u16)v7[k]);
    }
  }
  for (; j < n; ++j) {
    int s0 = csr[start + j];
    s16x4 v0 = *(const s16x4*)(Hs2 + (size_t)s0 * FOUT + p * 4);
    #pragma unroll
    for (int k = 0; k < 4; ++k) a0[k] += bf2f((u16)v0[k]);
  }

  float dd = dinv[d];
  float z[4];
  #pragma unroll
  for (int k = 0; k < 4; ++k)
    z[k] = ((a0[k]+a1[k]) + (a2[k]+a3[k])) * dd + b2[p * 4 + k];

  float m = fmaxf(fmaxf(z[0], z[1]), fmaxf(z[2], z[3]));
  m = fmaxf(m, __shfl_xor(m, 1));
  m = fmaxf(m, __shfl_xor(m, 2));
  float s = expf(z[0]-m) + expf(z[1]-m) + expf(z[2]-m) + expf(z[3]-m);
  s += __shfl_xor(s, 1);
  s += __shfl_xor(s, 2);
  float lse = m + logf(s);

  f32x4 o = { z[0]-lse, z[1]-lse, z[2]-lse, z[3]-lse };
  *(f32x4*)(out + (size_t)d * FOUT + p * 4) = o;
}

extern "C" void kernel_launch(void* const* d_in, const int* in_sizes, int n_in,
                              void* d_out, int out_size, void* d_ws, size_t ws_size,
                              hipStream_t stream) {
  const float* x  = (const float*)d_in[0];
  const float* W1 = (const float*)d_in[1];
  const float* b1 = (const float*)d_in[2];
  const float* W2 = (const float*)d_in[3];
  const float* b2 = (const float*)d_in[4];
  const int*   ei = (const int*)d_in[5];
  const int* srcv = ei;
  const int* dstv = ei + NE;

  char* ws = (char*)d_ws;
  const size_t KB = 1024, MB = 1048576;
  u32*   bcount = (u32*)(ws + 0);           // 784 B
  u32*   ticket = (u32*)(ws + 1 * KB);      // 4 B
  u32*   bstart = (u32*)(ws + 8 * KB);      // 788 B
  u32*   bcur   = (u32*)(ws + 16 * KB);     // 784 B
  int*   deg    = (int*)(ws + 512 * KB);    // 0.4 MB
  int*   rs     = (int*)(ws + 1024 * KB);   // 0.4 MB
  float* dinv   = (float*)(ws + 1536 * KB); // 0.4 MB
  u32*   binned = (u32*)(ws + 2 * MB);      // 6.4 MB
  int*   csr    = (int*)(ws + 9 * MB);      // 6.4 MB
  u16*   Hs1a   = (u16*)(ws + 16 * MB);     // 3.2 MB (bf16, cols 0-15, scaled)
  u16*   Hs1b   = (u16*)(ws + 20 * MB);     // 3.2 MB (bf16, cols 16-31, scaled)
  u16*   Hs2    = (u16*)(ws + 24 * MB);     // 3.2 MB (bf16)
  float* P2     = (float*)(ws + 28 * MB);   // 6.4 MB (f32 partial GEMM2)
  float* out    = (float*)d_out;

  hipMemsetAsync(ws, 0, 2 * KB, stream);    // bcount + ticket

  k_hist <<<NHB, 256, 0, stream>>>(dstv, bcount, ticket, bstart, bcur);
  k_bin  <<<NBB, 512, 0, stream>>>(srcv, dstv, bcur, binned);
  k_fin  <<<NBUCK, 256, 0, stream>>>(binned, bstart, deg, rs, dinv, csr);
  k_gemm1<<<782, 256, 0, stream>>>(x, W1, dinv, Hs1a, Hs1b);
  k_gat1a<<<(NN * 4 + 255) / 256, 256, 0, stream>>>(csr, rs, deg, dinv, b1, W2, Hs1a, P2);
  k_gat1b<<<(NN * 4 + 255) / 256, 256, 0, stream>>>(csr, rs, deg, dinv, b1, W2, Hs1b, P2, Hs2);
  k_gat2 <<<(NN * 4 + 255) / 256, 256, 0, stream>>>(csr, rs, deg, dinv, b2, Hs2, out);
}